// Round 1
// baseline (920.137 us; speedup 1.0000x reference)
//
#include <hip/hip_runtime.h>
#include <stdint.h>

// Problem constants (from reference): B=2, C=3, T=7, H=W=128, NHB=7, UF=4.
#define NHB   7
#define TT    7
#define HH    128
#define WW    128
#define BB    2
#define NU    16               // UF*UF channels before pixel shuffle
#define NTAPS (TT * NHB * NHB) // 343
#define NG    (TT * NHB)       // 49 (t,kh) groups of 7 kw-taps
#define WT    64               // w-tile per block
#define XSW   (WT + 6)         // 70: tile + 3-halo each side
#define XSWP  72               // padded row (8B-aligned float2 reads)
#define PLANE (NU * HH * WW)   // 262144 floats per filt tap plane (1 MB)
#define SLOTF (NHB * NU * WT)  // 7168 floats = 28 KB per LDS slot (7 taps x 16 u x 64 w)

// Fire-and-forget global->LDS DMA, 16B per lane. Global src is per-lane,
// LDS dest must be wave-uniform (lane i lands at dst + i*16).
__device__ __forceinline__ void gload16(const float* src, float* dst) {
    __builtin_amdgcn_global_load_lds(
        (const __attribute__((address_space(1))) void*)src,
        (__attribute__((address_space(3))) void*)dst,
        16, 0, 0);
}

// Block: (32 w-pairs, 16 u) = 512 threads. Grid: (2,128,2)=512 blocks.
// LDS 97.3 KB -> exactly 1 block/CU, two clean rounds over 256 CUs.
__global__ __launch_bounds__(512, 2)
void dynfilt_kernel(const float* __restrict__ x,
                    const float* __restrict__ filt,
                    float* __restrict__ out)
{
    __shared__ __align__(16) float xs[3][TT][NHB][XSWP];  // 42,336 B x halo tile
    __shared__ __align__(16) float fls[2][SLOTF];         // 57,344 B filt double buffer

    const int b     = blockIdx.z;
    const int h     = blockIdx.y;
    const int wbase = blockIdx.x * WT;
    const int tid   = threadIdx.y * 32 + threadIdx.x;

    // ---- one-time x halo tile stage (x is tiny: 2.75 MB total) ----
    for (int i = tid; i < 3 * TT * NHB * XSW; i += 512) {
        int wl   = i % XSW;
        int rest = i / XSW;
        int r    = rest % NHB; rest /= NHB;
        int t    = rest % TT;
        int c    = rest / TT;
        int gh = h + r - 3;
        int gw = wbase + wl - 3;
        float v = 0.0f;
        if (gh >= 0 && gh < HH && gw >= 0 && gw < WW)
            v = x[((((size_t)b * 3 + c) * TT + t) * HH + gh) * WW + gw];
        xs[c][t][r][wl] = v;
    }

    // ---- per-thread DMA source offsets ----
    // A 28KB slot = 1792 16B-chunks; chunk k = tid + 512*j (j=0..3; j=3 real only
    // for tid<256, i.e. waves 0-3 issue 4 DMA/slot, waves 4-7 issue 3).
    // k -> (tap q = k>>8, u = (k&255)>>4, 16B-col = k&15); global is 16B-aligned.
    const float* fb0 = filt + (size_t)b * NTAPS * PLANE;
    unsigned srcoff[4];
#pragma unroll
    for (int j = 0; j < 4; ++j) {
        const int k  = tid + 512 * j;
        const int q  = k >> 8;
        const int rr = k & 255;
        srcoff[j] = (unsigned)q * PLANE + (unsigned)(rr >> 4) * (HH * WW)
                  + (unsigned)h * WW + (unsigned)wbase + (unsigned)(rr & 15) * 4;
    }
    float* lwave = &fls[0][0] + (tid >> 6) * 256;   // wave-uniform LDS base

    __syncthreads();   // xs ready; vmcnt drained to 0 (bookkeeping baseline)

    auto stage = [&](int gg, int s) {
        const float* fg = fb0 + (size_t)gg * (NHB * PLANE);
        float* ld = lwave + s * SLOTF;
        gload16(fg + srcoff[0], ld);
        gload16(fg + srcoff[1], ld + 2048);
        gload16(fg + srcoff[2], ld + 4096);
        if (tid < 256) gload16(fg + srcoff[3], ld + 6144);   // tap q=6
    };

    // prologue: slots for groups 0 and 1 in flight (8 / 6 DMA outstanding)
    stage(0, 0);
    stage(1, 1);

    const int tx = threadIdx.x;   // 0..31 -> w-pair
    const int u  = threadIdx.y;   // 0..15 -> pre-shuffle channel
    const int w0 = wbase + 2 * tx;

    float acc00 = 0.f, acc01 = 0.f;   // color 0, pixels w0 / w0+1
    float acc10 = 0.f, acc11 = 0.f;
    float acc20 = 0.f, acc21 = 0.f;
    float den0  = 0.f, den1  = 0.f;

    const float* xbase = &xs[0][0][0][0] + 2 * tx;
    const float* fbr   = &fls[0][0] + u * WT + 2 * tx;   // filt slot read base

    auto consume = [&](int g, int s) {
        // filt taps for this (t,kh) group from LDS: 7 x ds_read_b64, 512B/wave,
        // conflict-free (lanes contiguous).
        const float2* fp2 = (const float2*)(fbr + s * SLOTF);
        float2 f[NHB];
#pragma unroll
        for (int q = 0; q < NHB; ++q) f[q] = fp2[q * (NU * WT / 2)];
        float xr[3][8];
#pragma unroll
        for (int c = 0; c < 3; ++c) {
            const float2* pp = (const float2*)(xbase + (c * NG + g) * XSWP);
            float2 v0 = pp[0], v1 = pp[1], v2 = pp[2], v3 = pp[3];
            xr[c][0] = v0.x; xr[c][1] = v0.y;
            xr[c][2] = v1.x; xr[c][3] = v1.y;
            xr[c][4] = v2.x; xr[c][5] = v2.y;
            xr[c][6] = v3.x; xr[c][7] = v3.y;
        }
#pragma unroll
        for (int kw = 0; kw < NHB; ++kw) {
            // N(0,1) logits: exp can't overflow fp32 -> skip max pass,
            // normalize by summed denominator at the end.
            float e0 = __expf(f[kw].x);
            float e1 = __expf(f[kw].y);
            den0 += e0; den1 += e1;
            acc00 += e0 * xr[0][kw];  acc01 += e1 * xr[0][kw + 1];
            acc10 += e0 * xr[1][kw];  acc11 += e1 * xr[1][kw + 1];
            acc20 += e0 * xr[2][kw];  acc21 += e1 * xr[2][kw + 1];
        }
    };

    // Counted-vmcnt discipline (per-wave): steady state outstanding = 8 (waves
    // 0-3) / 6 (waves 4-7); vmcnt(3) guarantees the consumed slot fully landed
    // for BOTH classes (4/slot: 8->3 drains slot+1 extra; 3/slot: 6->3 drains
    // slot exactly). Barrier after the wait joins all waves' guarantees.
    // lgkmcnt(0)+barrier before re-staging a slot: ds_reads must have retired
    // before DMA overwrites (s_barrier alone does NOT drain LDS queues).
#define WAIT_VM3  asm volatile("s_waitcnt vmcnt(3)" ::: "memory")
#define WAIT_VM0  asm volatile("s_waitcnt vmcnt(0)" ::: "memory")
#define WAIT_LGKM asm volatile("s_waitcnt lgkmcnt(0)" ::: "memory")
#define BAR       __builtin_amdgcn_s_barrier()

    for (int gp = 0; gp < 24; ++gp) {
        const int g = 2 * gp;
        WAIT_VM3; BAR;
        consume(g, 0);
        WAIT_LGKM; BAR;
        stage(g + 2, 0);                    // g+2 <= 48, even -> slot 0
        WAIT_VM3; BAR;
        consume(g + 1, 1);
        WAIT_LGKM; BAR;
        if (g + 3 < NG) stage(g + 3, 1);    // skipped only at gp=23
    }
    WAIT_VM0; BAR;                          // drain last slot (group 48)
    consume(NG - 1, 0);

    const float inv0 = 1.0f / den0;
    const float inv1 = 1.0f / den1;

    // pixel shuffle: out[b, c, 4h + (u>>2), 4w + (u&3)]
    const int r1 = u >> 2, r2 = u & 3;
    const int oh = h * 4 + r1;
    const float res[3][2] = {
        { acc00 * inv0, acc01 * inv1 },
        { acc10 * inv0, acc11 * inv1 },
        { acc20 * inv0, acc21 * inv1 },
    };
#pragma unroll
    for (int c = 0; c < 3; ++c) {
        size_t o = (((size_t)(b * 3 + c)) * (HH * 4) + oh) * (size_t)(WW * 4);
        out[o + (size_t)w0 * 4 + r2]       = res[c][0];
        out[o + (size_t)(w0 + 1) * 4 + r2] = res[c][1];
    }
}

extern "C" void kernel_launch(void* const* d_in, const int* in_sizes, int n_in,
                              void* d_out, int out_size, void* d_ws, size_t ws_size,
                              hipStream_t stream) {
    const float* x    = (const float*)d_in[0];   // [2,3,7,128,128] fp32
    const float* filt = (const float*)d_in[1];   // [2,343,16,128,128] fp32
    float* out        = (float*)d_out;           // [2,3,512,512] fp32

    dim3 grid(WW / WT, HH, BB);   // (2, 128, 2)
    dim3 block(32, NU);           // 512 threads
    dynfilt_kernel<<<grid, block, 0, stream>>>(x, filt, out);
}